// Round 1
// baseline (166.019 us; speedup 1.0000x reference)
//
#include <hip/hip_runtime.h>

// Problem constants
#define T_STEPS 128
#define BATCH   64
#define DIMX    32
#define S_SUP   1024
#define NROW    8192          // T*B
#define OUT_H_SZ   (T_STEPS*BATCH*4)      // 32768
#define OUT_RBF_SZ (NROW*S_SUP)           // 8388608

#define INV2PI 0.15915494309189535f
#define L2E    1.4426950408889634f

__device__ __forceinline__ float rcp_fast(float x)  { return __builtin_amdgcn_rcpf(x); }
__device__ __forceinline__ float exp2_fast(float x) { return __builtin_amdgcn_exp2f(x); }
// raw v_cos_f32: cos(2*pi*x). All angles are pre-scaled by 1/2pi upstream,
// so no per-use multiply (saves 4 VALU/step + one chain stage vs __cosf).
__device__ __forceinline__ float cos_rev(float x)   { return __builtin_amdgcn_cosf(x); }

// Intra-quad broadcast via DPP quad_perm (VALU latency, vs ~120 cy ds_bpermute)
template<int K>
__device__ __forceinline__ float quad_bcast(float v) {
    constexpr int ctrl = K * 0x55;   // K | K<<2 | K<<4 | K<<6
    return __builtin_bit_cast(float,
        __builtin_amdgcn_mov_dpp(__builtin_bit_cast(int, v), ctrl, 0xF, 0xF, true));
}

// tanh via Pade(5,4): x(945+105x^2+x^4)/(945+420x^2+15x^4).
// |c| <= 2.07 provably (f<=sigma(1), |u|<=tanh(1) => fixpoint 2.07); err <= 4e-5
// there -- far below the fast-exp path's own error. Removes one v_exp from the
// c->h dependent chain and 4 trans-unit ops/step.
__device__ __forceinline__ float tanh_pade(float x) {
    float q = x * x;
    float n = x * fmaf(q, q + 105.f, 945.f);
    float d = fmaf(q, fmaf(q, 15.f, 420.f), 945.f);
    return n * rcp_fast(d);
}

// ---------------------------------------------------------------------------
// Kernel 1: pre[row][g][w] = (b_g[w] + p_g[w] + sum_d x[row][d]*W_g[w][d]) / 2pi
// (pre-scaled to revolutions so the LSTM feeds v_cos directly)
// ---------------------------------------------------------------------------
__global__ __launch_bounds__(256) void pre_kernel(
    const float* __restrict__ x,
    const float* __restrict__ Wf, const float* __restrict__ bf,
    const float* __restrict__ Wi, const float* __restrict__ bi,
    const float* __restrict__ Wu, const float* __restrict__ bu,
    const float* __restrict__ Wo, const float* __restrict__ bo,
    const float* __restrict__ pf, const float* __restrict__ pi,
    const float* __restrict__ pu, const float* __restrict__ po,
    float* __restrict__ pre)
{
    const int tid = threadIdx.x;
    const int rl  = tid >> 4;          // 16 rows per block
    const int gw  = tid & 15;
    const int g   = gw >> 2, w = gw & 3;
    const int row = blockIdx.x * 16 + rl;

    __shared__ float xs[16 * DIMX];
    if (tid < 128) {
        ((float4*)xs)[tid] = ((const float4*)(x + (size_t)blockIdx.x * 16 * DIMX))[tid];
    }
    __syncthreads();

    const float* W  = (g == 0) ? Wf : (g == 1) ? Wi : (g == 2) ? Wu : Wo;
    const float* bb = (g == 0) ? bf : (g == 1) ? bi : (g == 2) ? bu : bo;
    const float* pp = (g == 0) ? pf : (g == 1) ? pi : (g == 2) ? pu : po;

    float acc = bb[w] + pp[w];
    const float* Wr = W + w * 36;      // row stride D+H = 36
    const float* xr = xs + rl * DIMX;
#pragma unroll
    for (int d = 0; d < DIMX; d++) acc += xr[d] * Wr[d];

    pre[(row * 4 + g) * 4 + w] = acc * INV2PI;
}

// ---------------------------------------------------------------------------
// Kernel 2 (fused, 512 threads/block):
//   block 0      = sequential LSTM, now 8 waves x 8 batches (2 chains/SIMD so
//                  issue of one wave fills the other's dependency stalls)
//   blocks 1..256 = rbf+qk tiles 32 n x 1024 s, 2 s-columns per thread
//                  (halves LDS ds_read_b128 traffic per output)
// ---------------------------------------------------------------------------
__global__ __launch_bounds__(512, 2) void fused_kernel(
    const float* __restrict__ x,  const float* __restrict__ sv,
    const float* __restrict__ Wf, const float* __restrict__ bf,
    const float* __restrict__ Wi, const float* __restrict__ bi,
    const float* __restrict__ Wu, const float* __restrict__ bu,
    const float* __restrict__ Wo, const float* __restrict__ bo,
    const float* __restrict__ pf, const float* __restrict__ pi,
    const float* __restrict__ pu, const float* __restrict__ po,
    const float* __restrict__ qkp, const float* __restrict__ pre,
    float* __restrict__ out_h, float* __restrict__ out_rbf, float* __restrict__ out_qk)
{
    __shared__ float xs[32 * DIMX];   // rbf path: 32-row x tile (4 KB)
    __shared__ float xn2[32];         // pre-scaled by -log2(e)
    const int tid = threadIdx.x;

    if (blockIdx.x == 0) {
        // ================= LSTM: 8 waves, each wave = 8 b x 4 g in lanes 0..31
        __builtin_amdgcn_s_setprio(3);   // win issue arbitration vs rbf waves
        const int lane = tid & 63;
        if (lane >= 32) return;          // upper half idle; no syncthreads here
        const int wv = tid >> 6;
        const int b  = wv * 8 + (lane >> 2);
        const int g  = lane & 3;
        const float* W = (g == 0) ? Wf : (g == 1) ? Wi : (g == 2) ? Wu : Wo;

        float Wh[4][4];                  // hidden part W[w][32+j], pre-scaled to revs
#pragma unroll
        for (int w = 0; w < 4; w++)
#pragma unroll
            for (int j = 0; j < 4; j++) Wh[w][j] = W[w * 36 + 32 + j] * INV2PI;

        // per-lane activation constants, log2e folded in:
        //   g!=2: sigmoid(r) = rcp(1+exp2(-L2E*r))
        //   g==2: tanh(r)    = 2*rcp(1+exp2(-2*L2E*r)) - 1
        const float K2 = (g == 2) ? (-2.f * L2E) : (-L2E);
        const float Aa = (g == 2) ?  2.f :  1.f;
        const float Bb = (g == 2) ? -1.f :  0.f;
        const bool  isg1 = (g == 1), isg2 = (g == 2), isg3 = (g == 3);

        float h0 = 0.f, h1 = 0.f, h2 = 0.f, h3 = 0.f;
        float c0 = 0.f, c1 = 0.f, c2 = 0.f, c3 = 0.f;
        const int base = b * 4 + g;          // float4 index inside one t slab (256/t)
        const float4* prep = (const float4*)pre;

        // One LSTM step on an already-loaded float4 (no loads, no branches).
        auto lstm_step = [&](int t, float4 cur) {
            float a0 = cur.x, a1 = cur.y, a2 = cur.z, a3 = cur.w;  // revolutions
            // hidden contribution (Wh pre-scaled)
            a0 += h0 * Wh[0][0] + h1 * Wh[0][1] + h2 * Wh[0][2] + h3 * Wh[0][3];
            a1 += h0 * Wh[1][0] + h1 * Wh[1][1] + h2 * Wh[1][2] + h3 * Wh[1][3];
            a2 += h0 * Wh[2][0] + h1 * Wh[2][1] + h2 * Wh[2][2] + h3 * Wh[2][3];
            a3 += h0 * Wh[3][0] + h1 * Wh[3][1] + h2 * Wh[3][2] + h3 * Wh[3][3];

            // closed-form circuit: C_w = cos(angle_w); PERM_WRAP-conjugated Z
            float C0 = cos_rev(a0), C1 = cos_rev(a1), C2 = cos_rev(a2), C3 = cos_rev(a3);
            float t23 = C2 * C3;
            float m01 = C0 * C1;
            float r0 = C1 * t23;     // <Z0> = C1 C2 C3
            float r1 = m01;          // <Z1> = C0 C1
            float r2 = m01 * C2;     // <Z2> = C0 C1 C2
            float r3 = m01 * t23;    // <Z3> = C0 C1 C2 C3

            // activation: mul, exp2, add, rcp, fma (log2e prefolded in K2)
            float o0 = fmaf(Aa, rcp_fast(1.f + exp2_fast(r0 * K2)), Bb);
            float o1 = fmaf(Aa, rcp_fast(1.f + exp2_fast(r1 * K2)), Bb);
            float o2 = fmaf(Aa, rcp_fast(1.f + exp2_fast(r2 * K2)), Bb);
            float o3 = fmaf(Aa, rcp_fast(1.f + exp2_fast(r3 * K2)), Bb);

            // gather f/i/u/o vectors from quad lanes (g = 0,1,2,3) via DPP
            float f0 = quad_bcast<0>(o0), f1 = quad_bcast<0>(o1), f2 = quad_bcast<0>(o2), f3 = quad_bcast<0>(o3);
            float i0 = quad_bcast<1>(o0), i1 = quad_bcast<1>(o1), i2 = quad_bcast<1>(o2), i3 = quad_bcast<1>(o3);
            float u0 = quad_bcast<2>(o0), u1 = quad_bcast<2>(o1), u2 = quad_bcast<2>(o2), u3 = quad_bcast<2>(o3);
            float z0 = quad_bcast<3>(o0), z1 = quad_bcast<3>(o1), z2 = quad_bcast<3>(o2), z3 = quad_bcast<3>(o3);

            c0 = f0 * c0 + i0 * u0;
            c1 = f1 * c1 + i1 * u1;
            c2 = f2 * c2 + i2 * u2;
            c3 = f3 * c3 + i3 * u3;

            // tanh(c) via Pade(5,4): no exp on the c->h chain, -4 trans ops
            float t0 = tanh_pade(c0);
            float t1 = tanh_pade(c1);
            float t2 = tanh_pade(c2);
            float t3 = tanh_pade(c3);
            h0 = z0 * t0; h1 = z1 * t1; h2 = z2 * t2; h3 = z3 * t3;

            // h is quad-uniform: lane (b,g) stores component g (coalesced,
            // UNCONDITIONAL -> static vmcnt tracking)
            float hsel = isg1 ? h1 : h0;
            hsel = isg2 ? h2 : hsel;
            hsel = isg3 ? h3 : hsel;
            out_h[t * 256 + base] = hsel;
        };

        // Chunked double-buffer: 8 cur + 8 nxt NAMED registers. All loads are
        // unconditional (last chunk clamps to re-read rows 120..127, unused),
        // issued a full chunk (~>1200 cy) before their consume.
        float4 cb0, cb1, cb2, cb3, cb4, cb5, cb6, cb7;
        cb0 = prep[base];           cb1 = prep[base + 256];
        cb2 = prep[base + 512];     cb3 = prep[base + 768];
        cb4 = prep[base + 1024];    cb5 = prep[base + 1280];
        cb6 = prep[base + 1536];    cb7 = prep[base + 1792];

#pragma unroll 1
        for (int tt = 0; tt < T_STEPS; tt += 8) {
            // issue next-chunk loads (branch-free clamped base)
            int nb = tt + 8; nb = (nb > T_STEPS - 8) ? (T_STEPS - 8) : nb;
            const float4* pc = prep + base + nb * 256;
            float4 nb0 = pc[0];
            float4 nb1 = pc[256];
            float4 nb2 = pc[512];
            float4 nb3 = pc[768];
            float4 nb4 = pc[1024];
            float4 nb5 = pc[1280];
            float4 nb6 = pc[1536];
            float4 nb7 = pc[1792];
            __builtin_amdgcn_sched_barrier(0);  // pin loads ahead of compute

            lstm_step(tt + 0, cb0);
            lstm_step(tt + 1, cb1);
            lstm_step(tt + 2, cb2);
            lstm_step(tt + 3, cb3);
            lstm_step(tt + 4, cb4);
            lstm_step(tt + 5, cb5);
            lstm_step(tt + 6, cb6);
            lstm_step(tt + 7, cb7);

            cb0 = nb0; cb1 = nb1; cb2 = nb2; cb3 = nb3;
            cb4 = nb4; cb5 = nb5; cb6 = nb6; cb7 = nb7;
        }
    } else {
        // ================= rbf + qk tile: 32 n x 1024 s, 2 s per thread ======
        const int bid = blockIdx.x - 1;
        const int n0  = bid * 32;

        float4* xs4 = (float4*)xs;
        const float4* xg = (const float4*)(x + (size_t)n0 * DIMX);
        if (tid < 256) {
            float4 t0v = xg[tid];
            xs4[tid] = t0v;
            // per-row |x|^2: 8 lanes per row, xor-reduce; store -log2e*|x|^2
            float p0 = t0v.x * t0v.x + t0v.y * t0v.y + t0v.z * t0v.z + t0v.w * t0v.w;
            p0 += __shfl_xor(p0, 1);
            p0 += __shfl_xor(p0, 2);
            p0 += __shfl_xor(p0, 4);
            if ((tid & 7) == 0) xn2[tid >> 3] = -L2E * p0;
        }

        // this thread's two support vectors (s and s+512)
        const int sA = tid, sB = tid + 512;
        float4 svv[8], svw[8];
        const float4* svgA = (const float4*)(sv + (size_t)sA * DIMX);
        const float4* svgB = (const float4*)(sv + (size_t)sB * DIMX);
#pragma unroll
        for (int k = 0; k < 8; k++) { svv[k] = svgA[k]; svw[k] = svgB[k]; }
        float sn2A = 0.f, sn2B = 0.f;
#pragma unroll
        for (int k = 0; k < 8; k++) {
            sn2A += svv[k].x * svv[k].x + svv[k].y * svv[k].y + svv[k].z * svv[k].z + svv[k].w * svv[k].w;
            sn2B += svw[k].x * svw[k].x + svw[k].y * svw[k].y + svw[k].z * svw[k].z + svw[k].w * svw[k].w;
        }
        const float snlA = -L2E * sn2A;
        const float snlB = -L2E * sn2B;

        // qk s-side: B_w = sv_w/2 + qk_w, pre-scaled to revolutions
        const float q0 = qkp[0], q1 = qkp[1], q2 = qkp[2], q3 = qkp[3];
        const float C05 = 0.5f * INV2PI;
        const float BA0 = fmaf(0.5f, svv[0].x, q0) * INV2PI;
        const float BA1 = fmaf(0.5f, svv[0].y, q1) * INV2PI;
        const float BA2 = fmaf(0.5f, svv[0].z, q2) * INV2PI;
        const float BA3 = fmaf(0.5f, svv[0].w, q3) * INV2PI;
        const float BB0 = fmaf(0.5f, svw[0].x, q0) * INV2PI;
        const float BB1 = fmaf(0.5f, svw[0].y, q1) * INV2PI;
        const float BB2 = fmaf(0.5f, svw[0].z, q2) * INV2PI;
        const float BB3 = fmaf(0.5f, svw[0].w, q3) * INV2PI;
        __syncthreads();

#pragma unroll 2
        for (int n = 0; n < 32; n++) {
            const float4* xr4 = (const float4*)(xs + n * DIMX);   // broadcast reads
            float4 xv0 = xr4[0];
            float dotA = xv0.x * svv[0].x + xv0.y * svv[0].y + xv0.z * svv[0].z + xv0.w * svv[0].w;
            float dotB = xv0.x * svw[0].x + xv0.y * svw[0].y + xv0.z * svw[0].z + xv0.w * svw[0].w;
#pragma unroll
            for (int k = 1; k < 8; k++) {
                float4 xv = xr4[k];
                dotA += xv.x * svv[k].x + xv.y * svv[k].y + xv.z * svv[k].z + xv.w * svv[k].w;
                dotB += xv.x * svw[k].x + xv.y * svw[k].y + xv.z * svw[k].z + xv.w * svw[k].w;
            }
            // rbf: exp(-(|x|^2+|s|^2-2dot)) = exp2(2*L2E*dot - L2E|x|^2 - L2E|s|^2)
            float xnl = xn2[n];
            float rbA = exp2_fast(fmaf(2.f * L2E, dotA, xnl + snlA));
            float rbB = exp2_fast(fmaf(2.f * L2E, dotB, xnl + snlB));

            float qvA = cos_rev(fmaf(C05, xv0.x, BA0)) * cos_rev(fmaf(C05, xv0.y, BA1))
                      * cos_rev(fmaf(C05, xv0.z, BA2)) * cos_rev(fmaf(C05, xv0.w, BA3));
            float qvB = cos_rev(fmaf(C05, xv0.x, BB0)) * cos_rev(fmaf(C05, xv0.y, BB1))
                      * cos_rev(fmaf(C05, xv0.z, BB2)) * cos_rev(fmaf(C05, xv0.w, BB3));
            qvA = fabsf(qvA);
            qvB = fabsf(qvB);

            const size_t rowb = (size_t)(n0 + n) * S_SUP;
            out_rbf[rowb + sA] = rbA;
            out_rbf[rowb + sB] = rbB;
            out_qk [rowb + sA] = qvA;
            out_qk [rowb + sB] = qvB;
        }
    }
}

// ---------------------------------------------------------------------------
extern "C" void kernel_launch(void* const* d_in, const int* in_sizes, int n_in,
                              void* d_out, int out_size, void* d_ws, size_t ws_size,
                              hipStream_t stream)
{
    const float* x   = (const float*)d_in[0];
    const float* sv  = (const float*)d_in[1];
    const float* Wf  = (const float*)d_in[2];
    const float* bf  = (const float*)d_in[3];
    const float* Wi  = (const float*)d_in[4];
    const float* bi  = (const float*)d_in[5];
    const float* Wu  = (const float*)d_in[6];
    const float* bu  = (const float*)d_in[7];
    const float* Wo  = (const float*)d_in[8];
    const float* bo  = (const float*)d_in[9];
    const float* pf  = (const float*)d_in[10];
    const float* pi  = (const float*)d_in[11];
    const float* pu  = (const float*)d_in[12];
    const float* po  = (const float*)d_in[13];
    const float* qkp = (const float*)d_in[14];

    float* out     = (float*)d_out;
    float* out_h   = out;
    float* out_rbf = out + OUT_H_SZ;
    float* out_qk  = out + OUT_H_SZ + OUT_RBF_SZ;

    float* pre = (float*)d_ws;   // 512 KB scratch (NROW*16 floats, in revolutions)

    pre_kernel<<<NROW / 16, 256, 0, stream>>>(x, Wf, bf, Wi, bi, Wu, bu, Wo, bo,
                                              pf, pi, pu, po, pre);
    fused_kernel<<<1 + 256, 512, 0, stream>>>(
        x, sv, Wf, bf, Wi, bi, Wu, bu, Wo, bo, pf, pi, pu, po, qkp, pre,
        out_h, out_rbf, out_qk);
}

// Round 2
// 143.789 us; speedup vs baseline: 1.1546x; 1.1546x over previous
//
#include <hip/hip_runtime.h>

// Problem constants
#define T_STEPS 128
#define BATCH   64
#define DIMX    32
#define S_SUP   1024
#define NROW    8192          // T*B
#define OUT_H_SZ   (T_STEPS*BATCH*4)      // 32768
#define OUT_RBF_SZ (NROW*S_SUP)           // 8388608

#define INV2PI 0.15915494309189535f
#define L2E    1.4426950408889634f

__device__ __forceinline__ float rcp_fast(float x)  { return __builtin_amdgcn_rcpf(x); }
__device__ __forceinline__ float exp2_fast(float x) { return __builtin_amdgcn_exp2f(x); }
// raw v_cos_f32: cos(2*pi*x). All angles pre-scaled by 1/2pi upstream.
__device__ __forceinline__ float cos_rev(float x)   { return __builtin_amdgcn_cosf(x); }

// Intra-quad broadcast via DPP quad_perm (VALU latency, vs ~120 cy ds_bpermute)
template<int K>
__device__ __forceinline__ float quad_bcast(float v) {
    constexpr int ctrl = K * 0x55;   // K | K<<2 | K<<4 | K<<6
    return __builtin_bit_cast(float,
        __builtin_amdgcn_mov_dpp(__builtin_bit_cast(int, v), ctrl, 0xF, 0xF, true));
}

// tanh via Pade(5,4): x(945+105x^2+x^4)/(945+420x^2+15x^4).
// Exact closed form (no fitted coeffs): err <= 4e-6 on [-1,1], <= 4e-5 at 2.07.
// 7 VALU + 1 v_rcp. Used for BOTH the gate activations (|r|<=1 since r is a
// product of cosines) and tanh(c) (|c|<=2.07 provably).
__device__ __forceinline__ float tanh_pade(float x) {
    float q = x * x;
    float n = x * fmaf(q, q + 105.f, 945.f);
    float d = fmaf(q, fmaf(q, 15.f, 420.f), 945.f);
    return n * rcp_fast(d);
}

// ---------------------------------------------------------------------------
// Kernel 1: pre[row][g][w] = (b_g[w] + p_g[w] + sum_d x[row][d]*W_g[w][d]) / 2pi
// (pre-scaled to revolutions so the LSTM feeds v_cos directly)
// ---------------------------------------------------------------------------
__global__ __launch_bounds__(256) void pre_kernel(
    const float* __restrict__ x,
    const float* __restrict__ Wf, const float* __restrict__ bf,
    const float* __restrict__ Wi, const float* __restrict__ bi,
    const float* __restrict__ Wu, const float* __restrict__ bu,
    const float* __restrict__ Wo, const float* __restrict__ bo,
    const float* __restrict__ pf, const float* __restrict__ pi,
    const float* __restrict__ pu, const float* __restrict__ po,
    float* __restrict__ pre)
{
    const int tid = threadIdx.x;
    const int rl  = tid >> 4;          // 16 rows per block
    const int gw  = tid & 15;
    const int g   = gw >> 2, w = gw & 3;
    const int row = blockIdx.x * 16 + rl;

    __shared__ float xs[16 * DIMX];
    if (tid < 128) {
        ((float4*)xs)[tid] = ((const float4*)(x + (size_t)blockIdx.x * 16 * DIMX))[tid];
    }
    __syncthreads();

    const float* W  = (g == 0) ? Wf : (g == 1) ? Wi : (g == 2) ? Wu : Wo;
    const float* bb = (g == 0) ? bf : (g == 1) ? bi : (g == 2) ? bu : bo;
    const float* pp = (g == 0) ? pf : (g == 1) ? pi : (g == 2) ? pu : po;

    float acc = bb[w] + pp[w];
    const float* Wr = W + w * 36;      // row stride D+H = 36
    const float* xr = xs + rl * DIMX;
#pragma unroll
    for (int d = 0; d < DIMX; d++) acc += xr[d] * Wr[d];

    pre[(row * 4 + g) * 4 + w] = acc * INV2PI;
}

// ---------------------------------------------------------------------------
// Kernel 2 (fused, 512 threads/block):
//   block 0      = sequential LSTM: 4 FULL waves (64 b x 4 g in 256 lanes,
//                  1 wave/SIMD). R1 lesson: half-empty waves double issue.
//   blocks 1..256 = rbf+qk tiles 32 n x 1024 s, 2 s-columns per thread
// ---------------------------------------------------------------------------
__global__ __launch_bounds__(512, 2) void fused_kernel(
    const float* __restrict__ x,  const float* __restrict__ sv,
    const float* __restrict__ Wf, const float* __restrict__ bf,
    const float* __restrict__ Wi, const float* __restrict__ bi,
    const float* __restrict__ Wu, const float* __restrict__ bu,
    const float* __restrict__ Wo, const float* __restrict__ bo,
    const float* __restrict__ pf, const float* __restrict__ pi,
    const float* __restrict__ pu, const float* __restrict__ po,
    const float* __restrict__ qkp, const float* __restrict__ pre,
    float* __restrict__ out_h, float* __restrict__ out_rbf, float* __restrict__ out_qk)
{
    __shared__ float xs[32 * DIMX];   // rbf path: 32-row x tile (4 KB)
    __shared__ float xn2[32];         // pre-scaled by -log2(e)
    const int tid = threadIdx.x;

    if (blockIdx.x == 0) {
        // ============ LSTM: thread = (b, g); 4 wires in-lane; 4 full waves ==
        if (tid >= 256) return;          // waves 4..7 idle (no barrier here)
        __builtin_amdgcn_s_setprio(3);   // win issue arbitration vs rbf waves
        const int b = tid >> 2, g = tid & 3;
        const float* W = (g == 0) ? Wf : (g == 1) ? Wi : (g == 2) ? Wu : Wo;

        float Wh[4][4];                  // hidden part W[w][32+j], pre-scaled to revs
#pragma unroll
        for (int w = 0; w < 4; w++)
#pragma unroll
            for (int j = 0; j < 4; j++) Wh[w][j] = W[w * 36 + 32 + j] * INV2PI;

        // Branch-free per-lane activation: act(r) = Aa * tanh_pade(Sc*r) + Bb
        //   sigmoid lanes (g!=2): Sc=0.5, Aa=0.5, Bb=0.5  (sigmoid = 0.5+0.5*tanh(r/2))
        //   tanh lane   (g==2):   Sc=1,   Aa=1,   Bb=0
        const float Sc = (g == 2) ? 1.f : 0.5f;
        const float Aa = (g == 2) ? 1.f : 0.5f;
        const float Bb = (g == 2) ? 0.f : 0.5f;
        const bool  isg1 = (g == 1), isg2 = (g == 2), isg3 = (g == 3);

        float h0 = 0.f, h1 = 0.f, h2 = 0.f, h3 = 0.f;
        float c0 = 0.f, c1 = 0.f, c2 = 0.f, c3 = 0.f;
        const int base = tid;                // float4 index inside one t slab (256/t)
        const float4* prep = (const float4*)pre;

        // One LSTM step on an already-loaded float4 (no loads, no branches).
        auto lstm_step = [&](int t, float4 cur) {
            float a0 = cur.x, a1 = cur.y, a2 = cur.z, a3 = cur.w;  // revolutions
            // hidden contribution (Wh pre-scaled)
            a0 += h0 * Wh[0][0] + h1 * Wh[0][1] + h2 * Wh[0][2] + h3 * Wh[0][3];
            a1 += h0 * Wh[1][0] + h1 * Wh[1][1] + h2 * Wh[1][2] + h3 * Wh[1][3];
            a2 += h0 * Wh[2][0] + h1 * Wh[2][1] + h2 * Wh[2][2] + h3 * Wh[2][3];
            a3 += h0 * Wh[3][0] + h1 * Wh[3][1] + h2 * Wh[3][2] + h3 * Wh[3][3];

            // closed-form circuit: C_w = cos(angle_w); PERM_WRAP-conjugated Z
            float C0 = cos_rev(a0), C1 = cos_rev(a1), C2 = cos_rev(a2), C3 = cos_rev(a3);
            float t23 = C2 * C3;
            float m01 = C0 * C1;
            float r0 = C1 * t23;     // <Z0> = C1 C2 C3
            float r1 = m01;          // <Z1> = C0 C1
            float r2 = m01 * C2;     // <Z2> = C0 C1 C2
            float r3 = m01 * t23;    // <Z3> = C0 C1 C2 C3

            // activation via Pade rational: 1 v_rcp each (vs exp2+rcp = 2 trans)
            float o0 = fmaf(Aa, tanh_pade(Sc * r0), Bb);
            float o1 = fmaf(Aa, tanh_pade(Sc * r1), Bb);
            float o2 = fmaf(Aa, tanh_pade(Sc * r2), Bb);
            float o3 = fmaf(Aa, tanh_pade(Sc * r3), Bb);

            // gather f/i/u/o vectors from quad lanes (g = 0,1,2,3) via DPP
            float f0 = quad_bcast<0>(o0), f1 = quad_bcast<0>(o1), f2 = quad_bcast<0>(o2), f3 = quad_bcast<0>(o3);
            float i0 = quad_bcast<1>(o0), i1 = quad_bcast<1>(o1), i2 = quad_bcast<1>(o2), i3 = quad_bcast<1>(o3);
            float u0 = quad_bcast<2>(o0), u1 = quad_bcast<2>(o1), u2 = quad_bcast<2>(o2), u3 = quad_bcast<2>(o3);
            float z0 = quad_bcast<3>(o0), z1 = quad_bcast<3>(o1), z2 = quad_bcast<3>(o2), z3 = quad_bcast<3>(o3);

            c0 = f0 * c0 + i0 * u0;
            c1 = f1 * c1 + i1 * u1;
            c2 = f2 * c2 + i2 * u2;
            c3 = f3 * c3 + i3 * u3;

            // tanh(c) via Pade(5,4): |c| <= 2.07 provably
            float t0 = tanh_pade(c0);
            float t1 = tanh_pade(c1);
            float t2 = tanh_pade(c2);
            float t3 = tanh_pade(c3);
            h0 = z0 * t0; h1 = z1 * t1; h2 = z2 * t2; h3 = z3 * t3;

            // h is quad-uniform: lane (b,g) stores component g (coalesced,
            // UNCONDITIONAL -> static vmcnt tracking)
            float hsel = isg1 ? h1 : h0;
            hsel = isg2 ? h2 : hsel;
            hsel = isg3 ? h3 : hsel;
            out_h[t * 256 + tid] = hsel;
        };

        // Chunked double-buffer: 8 cur + 8 nxt NAMED registers. All loads are
        // unconditional (last chunk clamps to re-read rows 120..127, unused),
        // issued a full chunk ahead of their consume.
        float4 cb0, cb1, cb2, cb3, cb4, cb5, cb6, cb7;
        cb0 = prep[base];           cb1 = prep[base + 256];
        cb2 = prep[base + 512];     cb3 = prep[base + 768];
        cb4 = prep[base + 1024];    cb5 = prep[base + 1280];
        cb6 = prep[base + 1536];    cb7 = prep[base + 1792];

#pragma unroll 1
        for (int tt = 0; tt < T_STEPS; tt += 8) {
            // issue next-chunk loads (branch-free clamped base)
            int nb = tt + 8; nb = (nb > T_STEPS - 8) ? (T_STEPS - 8) : nb;
            const float4* pc = prep + base + nb * 256;
            float4 nb0 = pc[0];
            float4 nb1 = pc[256];
            float4 nb2 = pc[512];
            float4 nb3 = pc[768];
            float4 nb4 = pc[1024];
            float4 nb5 = pc[1280];
            float4 nb6 = pc[1536];
            float4 nb7 = pc[1792];
            __builtin_amdgcn_sched_barrier(0);  // pin loads ahead of compute

            lstm_step(tt + 0, cb0);
            lstm_step(tt + 1, cb1);
            lstm_step(tt + 2, cb2);
            lstm_step(tt + 3, cb3);
            lstm_step(tt + 4, cb4);
            lstm_step(tt + 5, cb5);
            lstm_step(tt + 6, cb6);
            lstm_step(tt + 7, cb7);

            cb0 = nb0; cb1 = nb1; cb2 = nb2; cb3 = nb3;
            cb4 = nb4; cb5 = nb5; cb6 = nb6; cb7 = nb7;
        }
    } else {
        // ================= rbf + qk tile: 32 n x 1024 s, 2 s per thread ======
        const int bid = blockIdx.x - 1;
        const int n0  = bid * 32;

        float4* xs4 = (float4*)xs;
        const float4* xg = (const float4*)(x + (size_t)n0 * DIMX);
        if (tid < 256) {
            float4 t0v = xg[tid];
            xs4[tid] = t0v;
            // per-row |x|^2: 8 lanes per row, xor-reduce; store -log2e*|x|^2
            float p0 = t0v.x * t0v.x + t0v.y * t0v.y + t0v.z * t0v.z + t0v.w * t0v.w;
            p0 += __shfl_xor(p0, 1);
            p0 += __shfl_xor(p0, 2);
            p0 += __shfl_xor(p0, 4);
            if ((tid & 7) == 0) xn2[tid >> 3] = -L2E * p0;
        }

        // this thread's two support vectors (s and s+512)
        const int sA = tid, sB = tid + 512;
        float4 svv[8], svw[8];
        const float4* svgA = (const float4*)(sv + (size_t)sA * DIMX);
        const float4* svgB = (const float4*)(sv + (size_t)sB * DIMX);
#pragma unroll
        for (int k = 0; k < 8; k++) { svv[k] = svgA[k]; svw[k] = svgB[k]; }
        float sn2A = 0.f, sn2B = 0.f;
#pragma unroll
        for (int k = 0; k < 8; k++) {
            sn2A += svv[k].x * svv[k].x + svv[k].y * svv[k].y + svv[k].z * svv[k].z + svv[k].w * svv[k].w;
            sn2B += svw[k].x * svw[k].x + svw[k].y * svw[k].y + svw[k].z * svw[k].z + svw[k].w * svw[k].w;
        }
        const float snlA = -L2E * sn2A;
        const float snlB = -L2E * sn2B;

        // qk s-side: B_w = sv_w/2 + qk_w, pre-scaled to revolutions
        const float q0 = qkp[0], q1 = qkp[1], q2 = qkp[2], q3 = qkp[3];
        const float C05 = 0.5f * INV2PI;
        const float BA0 = fmaf(0.5f, svv[0].x, q0) * INV2PI;
        const float BA1 = fmaf(0.5f, svv[0].y, q1) * INV2PI;
        const float BA2 = fmaf(0.5f, svv[0].z, q2) * INV2PI;
        const float BA3 = fmaf(0.5f, svv[0].w, q3) * INV2PI;
        const float BB0 = fmaf(0.5f, svw[0].x, q0) * INV2PI;
        const float BB1 = fmaf(0.5f, svw[0].y, q1) * INV2PI;
        const float BB2 = fmaf(0.5f, svw[0].z, q2) * INV2PI;
        const float BB3 = fmaf(0.5f, svw[0].w, q3) * INV2PI;
        __syncthreads();

#pragma unroll 2
        for (int n = 0; n < 32; n++) {
            const float4* xr4 = (const float4*)(xs + n * DIMX);   // broadcast reads
            float4 xv0 = xr4[0];
            float dotA = xv0.x * svv[0].x + xv0.y * svv[0].y + xv0.z * svv[0].z + xv0.w * svv[0].w;
            float dotB = xv0.x * svw[0].x + xv0.y * svw[0].y + xv0.z * svw[0].z + xv0.w * svw[0].w;
#pragma unroll
            for (int k = 1; k < 8; k++) {
                float4 xv = xr4[k];
                dotA += xv.x * svv[k].x + xv.y * svv[k].y + xv.z * svv[k].z + xv.w * svv[k].w;
                dotB += xv.x * svw[k].x + xv.y * svw[k].y + xv.z * svw[k].z + xv.w * svw[k].w;
            }
            // rbf: exp(-(|x|^2+|s|^2-2dot)) = exp2(2*L2E*dot - L2E|x|^2 - L2E|s|^2)
            float xnl = xn2[n];
            float rbA = exp2_fast(fmaf(2.f * L2E, dotA, xnl + snlA));
            float rbB = exp2_fast(fmaf(2.f * L2E, dotB, xnl + snlB));

            float qvA = cos_rev(fmaf(C05, xv0.x, BA0)) * cos_rev(fmaf(C05, xv0.y, BA1))
                      * cos_rev(fmaf(C05, xv0.z, BA2)) * cos_rev(fmaf(C05, xv0.w, BA3));
            float qvB = cos_rev(fmaf(C05, xv0.x, BB0)) * cos_rev(fmaf(C05, xv0.y, BB1))
                      * cos_rev(fmaf(C05, xv0.z, BB2)) * cos_rev(fmaf(C05, xv0.w, BB3));
            qvA = fabsf(qvA);
            qvB = fabsf(qvB);

            const size_t rowb = (size_t)(n0 + n) * S_SUP;
            out_rbf[rowb + sA] = rbA;
            out_rbf[rowb + sB] = rbB;
            out_qk [rowb + sA] = qvA;
            out_qk [rowb + sB] = qvB;
        }
    }
}

// ---------------------------------------------------------------------------
extern "C" void kernel_launch(void* const* d_in, const int* in_sizes, int n_in,
                              void* d_out, int out_size, void* d_ws, size_t ws_size,
                              hipStream_t stream)
{
    const float* x   = (const float*)d_in[0];
    const float* sv  = (const float*)d_in[1];
    const float* Wf  = (const float*)d_in[2];
    const float* bf  = (const float*)d_in[3];
    const float* Wi  = (const float*)d_in[4];
    const float* bi  = (const float*)d_in[5];
    const float* Wu  = (const float*)d_in[6];
    const float* bu  = (const float*)d_in[7];
    const float* Wo  = (const float*)d_in[8];
    const float* bo  = (const float*)d_in[9];
    const float* pf  = (const float*)d_in[10];
    const float* pi  = (const float*)d_in[11];
    const float* pu  = (const float*)d_in[12];
    const float* po  = (const float*)d_in[13];
    const float* qkp = (const float*)d_in[14];

    float* out     = (float*)d_out;
    float* out_h   = out;
    float* out_rbf = out + OUT_H_SZ;
    float* out_qk  = out + OUT_H_SZ + OUT_RBF_SZ;

    float* pre = (float*)d_ws;   // 512 KB scratch (NROW*16 floats, in revolutions)

    pre_kernel<<<NROW / 16, 256, 0, stream>>>(x, Wf, bf, Wi, bi, Wu, bu, Wo, bo,
                                              pf, pi, pu, po, pre);
    fused_kernel<<<1 + 256, 512, 0, stream>>>(
        x, sv, Wf, bf, Wi, bi, Wu, bu, Wo, bo, pf, pi, pu, po, qkp, pre,
        out_h, out_rbf, out_qk);
}

// Round 3
// 134.895 us; speedup vs baseline: 1.2307x; 1.0659x over previous
//
#include <hip/hip_runtime.h>

// Problem constants
#define T_STEPS 128
#define BATCH   64
#define DIMX    32
#define S_SUP   1024
#define NROW    8192          // T*B
#define OUT_H_SZ   (T_STEPS*BATCH*4)      // 32768
#define OUT_RBF_SZ (NROW*S_SUP)           // 8388608

#define INV2PI 0.15915494309189535f
#define L2E    1.4426950408889634f

__device__ __forceinline__ float rcp_fast(float x)  { return __builtin_amdgcn_rcpf(x); }
__device__ __forceinline__ float exp2_fast(float x) { return __builtin_amdgcn_exp2f(x); }
// raw v_cos_f32: cos(2*pi*x). All angles pre-scaled by 1/2pi upstream.
__device__ __forceinline__ float cos_rev(float x)   { return __builtin_amdgcn_cosf(x); }

// DPP lane permutes within each quad (VALU-rate cross-lane)
template<int CTRL>
__device__ __forceinline__ float dpp_perm(float v) {
    return __builtin_bit_cast(float,
        __builtin_amdgcn_mov_dpp(__builtin_bit_cast(int, v), CTRL, 0xF, 0xF, true));
}
template<int K>
__device__ __forceinline__ float quad_bcast(float v) { return dpp_perm<K * 0x55>(v); }
#define DPP_XOR1 0xB1   // quad_perm [1,0,3,2]
#define DPP_XOR2 0x4E   // quad_perm [2,3,0,1]

// ---------------------------------------------------------------------------
// Kernel 1: pre[row][g][w] = (b_g[w] + p_g[w] + sum_d x[row][d]*W_g[w][d]) / 2pi
// (pre-scaled to revolutions so the LSTM feeds v_cos directly)
// ---------------------------------------------------------------------------
__global__ __launch_bounds__(256) void pre_kernel(
    const float* __restrict__ x,
    const float* __restrict__ Wf, const float* __restrict__ bf,
    const float* __restrict__ Wi, const float* __restrict__ bi,
    const float* __restrict__ Wu, const float* __restrict__ bu,
    const float* __restrict__ Wo, const float* __restrict__ bo,
    const float* __restrict__ pf, const float* __restrict__ pi,
    const float* __restrict__ pu, const float* __restrict__ po,
    float* __restrict__ pre)
{
    const int tid = threadIdx.x;
    const int rl  = tid >> 4;          // 16 rows per block
    const int gw  = tid & 15;
    const int g   = gw >> 2, w = gw & 3;
    const int row = blockIdx.x * 16 + rl;

    __shared__ float xs[16 * DIMX];
    if (tid < 128) {
        ((float4*)xs)[tid] = ((const float4*)(x + (size_t)blockIdx.x * 16 * DIMX))[tid];
    }
    __syncthreads();

    const float* W  = (g == 0) ? Wf : (g == 1) ? Wi : (g == 2) ? Wu : Wo;
    const float* bb = (g == 0) ? bf : (g == 1) ? bi : (g == 2) ? bu : bo;
    const float* pp = (g == 0) ? pf : (g == 1) ? pi : (g == 2) ? pu : po;

    float acc = bb[w] + pp[w];
    const float* Wr = W + w * 36;      // row stride D+H = 36
    const float* xr = xs + rl * DIMX;
#pragma unroll
    for (int d = 0; d < DIMX; d++) acc += xr[d] * Wr[d];

    pre[(row * 4 + g) * 4 + w] = acc * INV2PI;
}

// ---------------------------------------------------------------------------
// Kernel 2 (fused, 512 threads/block):
//   block 0      = sequential LSTM: 4 FULL waves, 1/SIMD, lane = (b,g).
//                  Gate compute in (b,g) layout, then a quad 4x4 TRANSPOSE so
//                  lane p owns wire p's state: tanh(c)/c/h computed ONCE, not
//                  quad-replicated. Empirical cost model (R0-R2 fit): ~8cy per
//                  VALU op, ~20cy per trans op, no ILP -> minimize op count.
//   blocks 1..256 = rbf+qk tiles 32 n x 1024 s, 2 s-columns per thread
// ---------------------------------------------------------------------------
__global__ __launch_bounds__(512, 2) void fused_kernel(
    const float* __restrict__ x,  const float* __restrict__ sv,
    const float* __restrict__ Wf, const float* __restrict__ bf,
    const float* __restrict__ Wi, const float* __restrict__ bi,
    const float* __restrict__ Wu, const float* __restrict__ bu,
    const float* __restrict__ Wo, const float* __restrict__ bo,
    const float* __restrict__ pf, const float* __restrict__ pi,
    const float* __restrict__ pu, const float* __restrict__ po,
    const float* __restrict__ qkp, const float* __restrict__ pre,
    float* __restrict__ out_h, float* __restrict__ out_rbf, float* __restrict__ out_qk)
{
    __shared__ float xs[32 * DIMX];   // rbf path: 32-row x tile (4 KB)
    __shared__ float xn2[32];         // pre-scaled by -log2(e)
    const int tid = threadIdx.x;

    if (blockIdx.x == 0) {
        // ============ LSTM: thread = (b, g); 4 full waves ===================
        if (tid >= 256) return;          // waves 4..7 idle (no barrier here)
        __builtin_amdgcn_s_setprio(3);   // win issue arbitration vs rbf waves
        const int b = tid >> 2, g = tid & 3;
        const float* W = (g == 0) ? Wf : (g == 1) ? Wi : (g == 2) ? Wu : Wo;

        float Wh[4][4];                  // hidden part W[w][32+j], pre-scaled to revs
#pragma unroll
        for (int w = 0; w < 4; w++)
#pragma unroll
            for (int j = 0; j < 4; j++) Wh[w][j] = W[w * 36 + 32 + j] * INV2PI;

        // per-lane activation constants (exp2 path, R0-proven):
        //   g!=2: sigmoid(r) = rcp(1+exp2(-L2E*r))
        //   g==2: tanh(r)    = 2*rcp(1+exp2(-2*L2E*r)) - 1
        const float K2 = (g == 2) ? (-2.f * L2E) : (-L2E);
        const float Aa = (g == 2) ?  2.f :  1.f;
        const float Bb = (g == 2) ? -1.f :  0.f;
        // transpose select bools (quad position bits)
        const bool lb0 = (tid & 1) != 0;
        const bool lb1 = (tid & 2) != 0;

        // state: this lane owns wire p = (tid&3) of batch b. Scalar h,c.
        float h = 0.f, c = 0.f;
        const int base = tid;                // float4 index inside one t slab (256/t)
        const float4* prep = (const float4*)pre;

        // One LSTM step on an already-loaded float4 (no loads, no branches).
        auto lstm_step = [&](int t, float4 cur) {
            // broadcast per-wire h across the quad (wire j lives in lane j)
            float hb0 = quad_bcast<0>(h);
            float hb1 = quad_bcast<1>(h);
            float hb2 = quad_bcast<2>(h);
            float hb3 = quad_bcast<3>(h);

            // angles for THIS lane's gate g, wires 0..3 (revolutions)
            float a0 = cur.x + hb0 * Wh[0][0] + hb1 * Wh[0][1] + hb2 * Wh[0][2] + hb3 * Wh[0][3];
            float a1 = cur.y + hb0 * Wh[1][0] + hb1 * Wh[1][1] + hb2 * Wh[1][2] + hb3 * Wh[1][3];
            float a2 = cur.z + hb0 * Wh[2][0] + hb1 * Wh[2][1] + hb2 * Wh[2][2] + hb3 * Wh[2][3];
            float a3 = cur.w + hb0 * Wh[3][0] + hb1 * Wh[3][1] + hb2 * Wh[3][2] + hb3 * Wh[3][3];

            // closed-form circuit: C_w = cos(angle_w); PERM_WRAP-conjugated Z
            float C0 = cos_rev(a0), C1 = cos_rev(a1), C2 = cos_rev(a2), C3 = cos_rev(a3);
            float t23 = C2 * C3;
            float m01 = C0 * C1;
            float r0 = C1 * t23;     // <Z0> = C1 C2 C3
            float r1 = m01;          // <Z1> = C0 C1
            float r2 = m01 * C2;     // <Z2> = C0 C1 C2
            float r3 = m01 * t23;    // <Z3> = C0 C1 C2 C3

            // activation (this lane's gate) for all 4 wires
            float o0 = fmaf(Aa, rcp_fast(1.f + exp2_fast(r0 * K2)), Bb);
            float o1 = fmaf(Aa, rcp_fast(1.f + exp2_fast(r1 * K2)), Bb);
            float o2 = fmaf(Aa, rcp_fast(1.f + exp2_fast(r2 * K2)), Bb);
            float o3 = fmaf(Aa, rcp_fast(1.f + exp2_fast(r3 * K2)), Bb);

            // ---- 4x4 quad butterfly transpose: M[g][w] -> B[w-lane][g-reg] --
            // stage 1: swap reg-pair (j, j^1) across lane-xor1
            float s0 = dpp_perm<DPP_XOR1>(o1);   // lane g gets M[g^1][1^0?]: M[g^1][j^1]
            float s1 = dpp_perm<DPP_XOR1>(o0);
            float s2 = dpp_perm<DPP_XOR1>(o3);
            float s3 = dpp_perm<DPP_XOR1>(o2);
            float A0 = lb0 ? s0 : o0;
            float A1 = lb0 ? o1 : s1;
            float A2 = lb0 ? s2 : o2;
            float A3 = lb0 ? o3 : s3;
            // stage 2: swap reg-pair (j, j^2) across lane-xor2
            float u0 = dpp_perm<DPP_XOR2>(A2);
            float u1 = dpp_perm<DPP_XOR2>(A3);
            float u2 = dpp_perm<DPP_XOR2>(A0);
            float u3 = dpp_perm<DPP_XOR2>(A1);
            float F = lb1 ? u0 : A0;   // gate f, this wire
            float I = lb1 ? u1 : A1;   // gate i
            float U = lb1 ? A2 : u2;   // gate u
            float O = lb1 ? A3 : u3;   // gate o

            // state update: ONCE per wire (no quad replication)
            c = fmaf(F, c, I * U);
            float e  = exp2_fast(c * (-2.f * L2E));
            float th = fmaf(2.f, rcp_fast(1.f + e), -1.f);
            h = O * th;

            // lane (b,p) stores wire p: out_h[t][b][w] -> coalesced, no select
            out_h[t * 256 + tid] = h;
        };

        // Chunked double-buffer: 8 cur + 8 nxt NAMED registers. All loads are
        // unconditional (last chunk clamps to re-read rows 120..127, unused),
        // issued a full chunk ahead of their consume.
        float4 cb0, cb1, cb2, cb3, cb4, cb5, cb6, cb7;
        cb0 = prep[base];           cb1 = prep[base + 256];
        cb2 = prep[base + 512];     cb3 = prep[base + 768];
        cb4 = prep[base + 1024];    cb5 = prep[base + 1280];
        cb6 = prep[base + 1536];    cb7 = prep[base + 1792];

#pragma unroll 1
        for (int tt = 0; tt < T_STEPS; tt += 8) {
            // issue next-chunk loads (branch-free clamped base)
            int nb = tt + 8; nb = (nb > T_STEPS - 8) ? (T_STEPS - 8) : nb;
            const float4* pc = prep + base + nb * 256;
            float4 nb0 = pc[0];
            float4 nb1 = pc[256];
            float4 nb2 = pc[512];
            float4 nb3 = pc[768];
            float4 nb4 = pc[1024];
            float4 nb5 = pc[1280];
            float4 nb6 = pc[1536];
            float4 nb7 = pc[1792];
            __builtin_amdgcn_sched_barrier(0);  // pin loads ahead of compute

            lstm_step(tt + 0, cb0);
            lstm_step(tt + 1, cb1);
            lstm_step(tt + 2, cb2);
            lstm_step(tt + 3, cb3);
            lstm_step(tt + 4, cb4);
            lstm_step(tt + 5, cb5);
            lstm_step(tt + 6, cb6);
            lstm_step(tt + 7, cb7);

            cb0 = nb0; cb1 = nb1; cb2 = nb2; cb3 = nb3;
            cb4 = nb4; cb5 = nb5; cb6 = nb6; cb7 = nb7;
        }
    } else {
        // ================= rbf + qk tile: 32 n x 1024 s, 2 s per thread ======
        const int bid = blockIdx.x - 1;
        const int n0  = bid * 32;

        float4* xs4 = (float4*)xs;
        const float4* xg = (const float4*)(x + (size_t)n0 * DIMX);
        if (tid < 256) {
            float4 t0v = xg[tid];
            xs4[tid] = t0v;
            // per-row |x|^2: 8 lanes per row, xor-reduce; store -log2e*|x|^2
            float p0 = t0v.x * t0v.x + t0v.y * t0v.y + t0v.z * t0v.z + t0v.w * t0v.w;
            p0 += __shfl_xor(p0, 1);
            p0 += __shfl_xor(p0, 2);
            p0 += __shfl_xor(p0, 4);
            if ((tid & 7) == 0) xn2[tid >> 3] = -L2E * p0;
        }

        // this thread's two support vectors (s and s+512)
        const int sA = tid, sB = tid + 512;
        float4 svv[8], svw[8];
        const float4* svgA = (const float4*)(sv + (size_t)sA * DIMX);
        const float4* svgB = (const float4*)(sv + (size_t)sB * DIMX);
#pragma unroll
        for (int k = 0; k < 8; k++) { svv[k] = svgA[k]; svw[k] = svgB[k]; }
        float sn2A = 0.f, sn2B = 0.f;
#pragma unroll
        for (int k = 0; k < 8; k++) {
            sn2A += svv[k].x * svv[k].x + svv[k].y * svv[k].y + svv[k].z * svv[k].z + svv[k].w * svv[k].w;
            sn2B += svw[k].x * svw[k].x + svw[k].y * svw[k].y + svw[k].z * svw[k].z + svw[k].w * svw[k].w;
        }
        const float snlA = -L2E * sn2A;
        const float snlB = -L2E * sn2B;

        // qk s-side: B_w = sv_w/2 + qk_w, pre-scaled to revolutions
        const float q0 = qkp[0], q1 = qkp[1], q2 = qkp[2], q3 = qkp[3];
        const float C05 = 0.5f * INV2PI;
        const float BA0 = fmaf(0.5f, svv[0].x, q0) * INV2PI;
        const float BA1 = fmaf(0.5f, svv[0].y, q1) * INV2PI;
        const float BA2 = fmaf(0.5f, svv[0].z, q2) * INV2PI;
        const float BA3 = fmaf(0.5f, svv[0].w, q3) * INV2PI;
        const float BB0 = fmaf(0.5f, svw[0].x, q0) * INV2PI;
        const float BB1 = fmaf(0.5f, svw[0].y, q1) * INV2PI;
        const float BB2 = fmaf(0.5f, svw[0].z, q2) * INV2PI;
        const float BB3 = fmaf(0.5f, svw[0].w, q3) * INV2PI;
        __syncthreads();

#pragma unroll 2
        for (int n = 0; n < 32; n++) {
            const float4* xr4 = (const float4*)(xs + n * DIMX);   // broadcast reads
            float4 xv0 = xr4[0];
            float dotA = xv0.x * svv[0].x + xv0.y * svv[0].y + xv0.z * svv[0].z + xv0.w * svv[0].w;
            float dotB = xv0.x * svw[0].x + xv0.y * svw[0].y + xv0.z * svw[0].z + xv0.w * svw[0].w;
#pragma unroll
            for (int k = 1; k < 8; k++) {
                float4 xv = xr4[k];
                dotA += xv.x * svv[k].x + xv.y * svv[k].y + xv.z * svv[k].z + xv.w * svv[k].w;
                dotB += xv.x * svw[k].x + xv.y * svw[k].y + xv.z * svw[k].z + xv.w * svw[k].w;
            }
            // rbf: exp(-(|x|^2+|s|^2-2dot)) = exp2(2*L2E*dot - L2E|x|^2 - L2E|s|^2)
            float xnl = xn2[n];
            float rbA = exp2_fast(fmaf(2.f * L2E, dotA, xnl + snlA));
            float rbB = exp2_fast(fmaf(2.f * L2E, dotB, xnl + snlB));

            float qvA = cos_rev(fmaf(C05, xv0.x, BA0)) * cos_rev(fmaf(C05, xv0.y, BA1))
                      * cos_rev(fmaf(C05, xv0.z, BA2)) * cos_rev(fmaf(C05, xv0.w, BA3));
            float qvB = cos_rev(fmaf(C05, xv0.x, BB0)) * cos_rev(fmaf(C05, xv0.y, BB1))
                      * cos_rev(fmaf(C05, xv0.z, BB2)) * cos_rev(fmaf(C05, xv0.w, BB3));
            qvA = fabsf(qvA);
            qvB = fabsf(qvB);

            const size_t rowb = (size_t)(n0 + n) * S_SUP;
            out_rbf[rowb + sA] = rbA;
            out_rbf[rowb + sB] = rbB;
            out_qk [rowb + sA] = qvA;
            out_qk [rowb + sB] = qvB;
        }
    }
}

// ---------------------------------------------------------------------------
extern "C" void kernel_launch(void* const* d_in, const int* in_sizes, int n_in,
                              void* d_out, int out_size, void* d_ws, size_t ws_size,
                              hipStream_t stream)
{
    const float* x   = (const float*)d_in[0];
    const float* sv  = (const float*)d_in[1];
    const float* Wf  = (const float*)d_in[2];
    const float* bf  = (const float*)d_in[3];
    const float* Wi  = (const float*)d_in[4];
    const float* bi  = (const float*)d_in[5];
    const float* Wu  = (const float*)d_in[6];
    const float* bu  = (const float*)d_in[7];
    const float* Wo  = (const float*)d_in[8];
    const float* bo  = (const float*)d_in[9];
    const float* pf  = (const float*)d_in[10];
    const float* pi  = (const float*)d_in[11];
    const float* pu  = (const float*)d_in[12];
    const float* po  = (const float*)d_in[13];
    const float* qkp = (const float*)d_in[14];

    float* out     = (float*)d_out;
    float* out_h   = out;
    float* out_rbf = out + OUT_H_SZ;
    float* out_qk  = out + OUT_H_SZ + OUT_RBF_SZ;

    float* pre = (float*)d_ws;   // 512 KB scratch (NROW*16 floats, in revolutions)

    pre_kernel<<<NROW / 16, 256, 0, stream>>>(x, Wf, bf, Wi, bi, Wu, bu, Wo, bo,
                                              pf, pi, pu, po, pre);
    fused_kernel<<<1 + 256, 512, 0, stream>>>(
        x, sv, Wf, bf, Wi, bi, Wu, bu, Wo, bo, pf, pi, pu, po, qkp, pre,
        out_h, out_rbf, out_qk);
}

// Round 4
// 132.822 us; speedup vs baseline: 1.2499x; 1.0156x over previous
//
#include <hip/hip_runtime.h>

// Problem constants
#define T_STEPS 128
#define BATCH   64
#define DIMX    32
#define S_SUP   1024
#define NROW    8192          // T*B
#define OUT_H_SZ   (T_STEPS*BATCH*4)      // 32768
#define OUT_RBF_SZ (NROW*S_SUP)           // 8388608

#define INV2PI 0.15915494309189535f
#define L2E    1.4426950408889634f

__device__ __forceinline__ float rcp_fast(float x)  { return __builtin_amdgcn_rcpf(x); }
__device__ __forceinline__ float exp2_fast(float x) { return __builtin_amdgcn_exp2f(x); }
// raw v_cos_f32: cos(2*pi*x). All angles pre-scaled by 1/2pi upstream.
__device__ __forceinline__ float cos_rev(float x)   { return __builtin_amdgcn_cosf(x); }

// DPP lane permutes within each quad (VALU-rate cross-lane)
template<int CTRL>
__device__ __forceinline__ float dpp_perm(float v) {
    return __builtin_bit_cast(float,
        __builtin_amdgcn_mov_dpp(__builtin_bit_cast(int, v), CTRL, 0xF, 0xF, true));
}
#define DPP_XOR1 0xB1   // quad_perm [1,0,3,2]

// ds_swizzle BitMode: src_lane = ((lane & and) | or) ^ xor, offset = xor<<10|or<<5|and
template<int OFF>
__device__ __forceinline__ float swz(float v) {
    return __builtin_bit_cast(float,
        __builtin_amdgcn_ds_swizzle(__builtin_bit_cast(int, v), OFF));
}

// ---------------------------------------------------------------------------
// Kernel 1: pre[row][g][w] = (b_g[w] + p_g[w] + sum_d x[row][d]*W_g[w][d]) / 2pi
// (pre-scaled to revolutions so the LSTM feeds v_cos directly)
// ---------------------------------------------------------------------------
__global__ __launch_bounds__(256) void pre_kernel(
    const float* __restrict__ x,
    const float* __restrict__ Wf, const float* __restrict__ bf,
    const float* __restrict__ Wi, const float* __restrict__ bi,
    const float* __restrict__ Wu, const float* __restrict__ bu,
    const float* __restrict__ Wo, const float* __restrict__ bo,
    const float* __restrict__ pf, const float* __restrict__ pi,
    const float* __restrict__ pu, const float* __restrict__ po,
    float* __restrict__ pre)
{
    const int tid = threadIdx.x;
    const int rl  = tid >> 4;          // 16 rows per block
    const int gw  = tid & 15;
    const int g   = gw >> 2, w = gw & 3;
    const int row = blockIdx.x * 16 + rl;

    __shared__ float xs[16 * DIMX];
    if (tid < 128) {
        ((float4*)xs)[tid] = ((const float4*)(x + (size_t)blockIdx.x * 16 * DIMX))[tid];
    }
    __syncthreads();

    const float* W  = (g == 0) ? Wf : (g == 1) ? Wi : (g == 2) ? Wu : Wo;
    const float* bb = (g == 0) ? bf : (g == 1) ? bi : (g == 2) ? bu : bo;
    const float* pp = (g == 0) ? pf : (g == 1) ? pi : (g == 2) ? pu : po;

    float acc = bb[w] + pp[w];
    const float* Wr = W + w * 36;      // row stride D+H = 36
    const float* xr = xs + rl * DIMX;
#pragma unroll
    for (int d = 0; d < DIMX; d++) acc += xr[d] * Wr[d];

    pre[(row * 4 + g) * 4 + w] = acc * INV2PI;
}

// ---------------------------------------------------------------------------
// Kernel 2 (fused, 512 threads/block):
//   block 0 = sequential LSTM, 8 FULL waves (2/SIMD). R1 measured that a 2nd
//     co-resident wave's ops are nearly free (interleave at the SIMD arbiter),
//     R1-R3 measured a lone in-order wave pays ~8cy/VALU ~23cy/trans with no
//     ILP. So: halve per-lane work, double waves. Unit = (batch, gate, wpair):
//     lane e=lane&7 -> gate g=e>>1, wirepair wp=e&1 (wires 2wp,2wp+1).
//     Post-transpose, lane owns wire w_own = 2*wp + (e>>2) (x2 duplicated).
//     Cross-lane: ds_swizzle within the 8-lane group + 1 quad-DPP.
//     State kept as c' = -2*log2e*c (U' pre-scaled in g==2 act consts) so
//     tanh(c) = 2*rcp(1+exp2(c'))-1 with no mul on the c->h chain.
//   blocks 1..256 = rbf+qk tiles 32 n x 1024 s, 2 s-columns per thread
// ---------------------------------------------------------------------------
__global__ __launch_bounds__(512, 2) void fused_kernel(
    const float* __restrict__ x,  const float* __restrict__ sv,
    const float* __restrict__ Wf, const float* __restrict__ bf,
    const float* __restrict__ Wi, const float* __restrict__ bi,
    const float* __restrict__ Wu, const float* __restrict__ bu,
    const float* __restrict__ Wo, const float* __restrict__ bo,
    const float* __restrict__ pf, const float* __restrict__ pi,
    const float* __restrict__ pu, const float* __restrict__ po,
    const float* __restrict__ qkp, const float* __restrict__ pre,
    float* __restrict__ out_h, float* __restrict__ out_rbf, float* __restrict__ out_qk)
{
    __shared__ float xs[32 * DIMX];   // rbf path: 32-row x tile (4 KB)
    __shared__ float xn2[32];         // pre-scaled by -log2(e)
    const int tid = threadIdx.x;

    if (blockIdx.x == 0) {
        // ============ LSTM: 8 full waves, unit = (b, g, wp) =================
        __builtin_amdgcn_s_setprio(3);   // win issue arbitration vs rbf waves
        const int lane = tid & 63;
        const int wv   = tid >> 6;             // wave 0..7
        const int g    = (lane >> 1) & 3;      // gate
        const int wp   = lane & 1;             // wire pair (wires 2wp, 2wp+1)
        const bool iswp = wp != 0;
        const bool hi2  = (lane & 4) != 0;     // reg-select for transpose
        const int b     = wv * 8 + (lane >> 3);
        const int wown  = 2 * wp + ((lane >> 2) & 1);   // owned wire (dup x2)
        const int hbase = b * 4 + wown;

        const float* W = (g == 0) ? Wf : (g == 1) ? Wi : (g == 2) ? Wu : Wo;
        float WhA[4], WhB[4];            // hidden rows for wires 2wp, 2wp+1
        const int wA = 2 * wp;
#pragma unroll
        for (int j = 0; j < 4; j++) {
            WhA[j] = W[ wA      * 36 + 32 + j] * INV2PI;
            WhB[j] = W[(wA + 1) * 36 + 32 + j] * INV2PI;
        }

        // act consts: g!=2 sigmoid; g==2 produces U' = -2*L2E*tanh(r)
        const float K2 = (g == 2) ? (-2.f * L2E) : (-L2E);
        const float Aa = (g == 2) ? (-4.f * L2E) : 1.f;
        const float Bb = (g == 2) ? ( 2.f * L2E) : 0.f;

        float h = 0.f, cs = 0.f;         // cs = -2*L2E * c
        const float2* prep2 = (const float2*)pre;

        // One LSTM step on an already-loaded float2 (this lane's 2 wires).
        auto lstm_step = [&](int t, float2 cur) {
            // gather h0..h3 from owner lanes e={0,4,1,5} (wires 0,1,2,3)
            float h0 = swz<0x018>(h);
            float h1 = swz<0x098>(h);
            float h2 = swz<0x038>(h);
            float h3 = swz<0x0B8>(h);

            // angles (revolutions) for this gate's wires 2wp, 2wp+1
            float aA = cur.x + h0 * WhA[0] + h1 * WhA[1] + h2 * WhA[2] + h3 * WhA[3];
            float aB = cur.y + h0 * WhB[0] + h1 * WhB[1] + h2 * WhB[2] + h3 * WhB[3];
            float CA = cos_rev(aA), CB = cos_rev(aB);

            // partner pair's cosines (same gate, other wp) via quad DPP xor1
            float DA = dpp_perm<DPP_XOR1>(CA);
            float DB = dpp_perm<DPP_XOR1>(CB);

            // r for this lane's 2 wires:
            //  wp0: rA=r0=C1*C2*C3, rB=r1=C0*C1 ; wp1: rA=r2=C0*C1*C2, rB=r3=rA*C3
            float P  = DA * DB;
            float t1 = iswp ? CA : CB;
            float rA = t1 * P;
            float t2 = iswp ? rA : CA;
            float rB = t2 * CB;

            // activations (this gate), exp2 path
            float sA = rcp_fast(1.f + exp2_fast(rA * K2));
            float sB = rcp_fast(1.f + exp2_fast(rB * K2));
            float oA = fmaf(Aa, sA, Bb);
            float oB = fmaf(Aa, sB, Bb);

            // gate-transpose: gather all 4 gates' acts for my wire.
            // src lane = (lane & 0b11001) | (gate<<1); take reg A if wown even
            float FA = swz<0x019>(oA), FB = swz<0x019>(oB);
            float IA = swz<0x059>(oA), IB = swz<0x059>(oB);
            float UA = swz<0x099>(oA), UB = swz<0x099>(oB);
            float OA = swz<0x0D9>(oA), OB = swz<0x0D9>(oB);
            float F = hi2 ? FB : FA;
            float I = hi2 ? IB : IA;
            float U = hi2 ? UB : UA;     // already scaled: U' = -2*L2E*u
            float O = hi2 ? OB : OA;

            // state update (c' recurrence), tanh via exp2(c') directly
            cs = fmaf(F, cs, I * U);
            float th = fmaf(2.f, rcp_fast(1.f + exp2_fast(cs)), -1.f);
            h = O * th;

            // both dup lanes store the same value (same address, harmless)
            out_h[t * 256 + hbase] = h;
        };

        // Chunked double-buffer: 8 cur + 8 nxt float2 regs; loads issued a
        // full chunk ahead. prep2 index for step t is simply t*512 + tid.
        float2 cb0, cb1, cb2, cb3, cb4, cb5, cb6, cb7;
        cb0 = prep2[tid];            cb1 = prep2[tid + 512];
        cb2 = prep2[tid + 1024];     cb3 = prep2[tid + 1536];
        cb4 = prep2[tid + 2048];     cb5 = prep2[tid + 2560];
        cb6 = prep2[tid + 3072];     cb7 = prep2[tid + 3584];

#pragma unroll 1
        for (int tt = 0; tt < T_STEPS; tt += 8) {
            // issue next-chunk loads (branch-free clamped base)
            int nb = tt + 8; nb = (nb > T_STEPS - 8) ? (T_STEPS - 8) : nb;
            const float2* pc = prep2 + tid + nb * 512;
            float2 nb0 = pc[0];
            float2 nb1 = pc[512];
            float2 nb2 = pc[1024];
            float2 nb3 = pc[1536];
            float2 nb4 = pc[2048];
            float2 nb5 = pc[2560];
            float2 nb6 = pc[3072];
            float2 nb7 = pc[3584];
            __builtin_amdgcn_sched_barrier(0);  // pin loads ahead of compute

            lstm_step(tt + 0, cb0);
            lstm_step(tt + 1, cb1);
            lstm_step(tt + 2, cb2);
            lstm_step(tt + 3, cb3);
            lstm_step(tt + 4, cb4);
            lstm_step(tt + 5, cb5);
            lstm_step(tt + 6, cb6);
            lstm_step(tt + 7, cb7);

            cb0 = nb0; cb1 = nb1; cb2 = nb2; cb3 = nb3;
            cb4 = nb4; cb5 = nb5; cb6 = nb6; cb7 = nb7;
        }
    } else {
        // ================= rbf + qk tile: 32 n x 1024 s, 2 s per thread ======
        const int bid = blockIdx.x - 1;
        const int n0  = bid * 32;

        float4* xs4 = (float4*)xs;
        const float4* xg = (const float4*)(x + (size_t)n0 * DIMX);
        if (tid < 256) {
            float4 t0v = xg[tid];
            xs4[tid] = t0v;
            // per-row |x|^2: 8 lanes per row, xor-reduce; store -log2e*|x|^2
            float p0 = t0v.x * t0v.x + t0v.y * t0v.y + t0v.z * t0v.z + t0v.w * t0v.w;
            p0 += __shfl_xor(p0, 1);
            p0 += __shfl_xor(p0, 2);
            p0 += __shfl_xor(p0, 4);
            if ((tid & 7) == 0) xn2[tid >> 3] = -L2E * p0;
        }

        // this thread's two support vectors (s and s+512)
        const int sA = tid, sB = tid + 512;
        float4 svv[8], svw[8];
        const float4* svgA = (const float4*)(sv + (size_t)sA * DIMX);
        const float4* svgB = (const float4*)(sv + (size_t)sB * DIMX);
#pragma unroll
        for (int k = 0; k < 8; k++) { svv[k] = svgA[k]; svw[k] = svgB[k]; }
        float sn2A = 0.f, sn2B = 0.f;
#pragma unroll
        for (int k = 0; k < 8; k++) {
            sn2A += svv[k].x * svv[k].x + svv[k].y * svv[k].y + svv[k].z * svv[k].z + svv[k].w * svv[k].w;
            sn2B += svw[k].x * svw[k].x + svw[k].y * svw[k].y + svw[k].z * svw[k].z + svw[k].w * svw[k].w;
        }
        const float snlA = -L2E * sn2A;
        const float snlB = -L2E * sn2B;

        // qk s-side: B_w = sv_w/2 + qk_w, pre-scaled to revolutions
        const float q0 = qkp[0], q1 = qkp[1], q2 = qkp[2], q3 = qkp[3];
        const float C05 = 0.5f * INV2PI;
        const float BA0 = fmaf(0.5f, svv[0].x, q0) * INV2PI;
        const float BA1 = fmaf(0.5f, svv[0].y, q1) * INV2PI;
        const float BA2 = fmaf(0.5f, svv[0].z, q2) * INV2PI;
        const float BA3 = fmaf(0.5f, svv[0].w, q3) * INV2PI;
        const float BB0 = fmaf(0.5f, svw[0].x, q0) * INV2PI;
        const float BB1 = fmaf(0.5f, svw[0].y, q1) * INV2PI;
        const float BB2 = fmaf(0.5f, svw[0].z, q2) * INV2PI;
        const float BB3 = fmaf(0.5f, svw[0].w, q3) * INV2PI;
        __syncthreads();

#pragma unroll 2
        for (int n = 0; n < 32; n++) {
            const float4* xr4 = (const float4*)(xs + n * DIMX);   // broadcast reads
            float4 xv0 = xr4[0];
            float dotA = xv0.x * svv[0].x + xv0.y * svv[0].y + xv0.z * svv[0].z + xv0.w * svv[0].w;
            float dotB = xv0.x * svw[0].x + xv0.y * svw[0].y + xv0.z * svw[0].z + xv0.w * svw[0].w;
#pragma unroll
            for (int k = 1; k < 8; k++) {
                float4 xv = xr4[k];
                dotA += xv.x * svv[k].x + xv.y * svv[k].y + xv.z * svv[k].z + xv.w * svv[k].w;
                dotB += xv.x * svw[k].x + xv.y * svw[k].y + xv.z * svw[k].z + xv.w * svw[k].w;
            }
            // rbf: exp(-(|x|^2+|s|^2-2dot)) = exp2(2*L2E*dot - L2E|x|^2 - L2E|s|^2)
            float xnl = xn2[n];
            float rbA = exp2_fast(fmaf(2.f * L2E, dotA, xnl + snlA));
            float rbB = exp2_fast(fmaf(2.f * L2E, dotB, xnl + snlB));

            float qvA = cos_rev(fmaf(C05, xv0.x, BA0)) * cos_rev(fmaf(C05, xv0.y, BA1))
                      * cos_rev(fmaf(C05, xv0.z, BA2)) * cos_rev(fmaf(C05, xv0.w, BA3));
            float qvB = cos_rev(fmaf(C05, xv0.x, BB0)) * cos_rev(fmaf(C05, xv0.y, BB1))
                      * cos_rev(fmaf(C05, xv0.z, BB2)) * cos_rev(fmaf(C05, xv0.w, BB3));
            qvA = fabsf(qvA);
            qvB = fabsf(qvB);

            const size_t rowb = (size_t)(n0 + n) * S_SUP;
            out_rbf[rowb + sA] = rbA;
            out_rbf[rowb + sB] = rbB;
            out_qk [rowb + sA] = qvA;
            out_qk [rowb + sB] = qvB;
        }
    }
}

// ---------------------------------------------------------------------------
extern "C" void kernel_launch(void* const* d_in, const int* in_sizes, int n_in,
                              void* d_out, int out_size, void* d_ws, size_t ws_size,
                              hipStream_t stream)
{
    const float* x   = (const float*)d_in[0];
    const float* sv  = (const float*)d_in[1];
    const float* Wf  = (const float*)d_in[2];
    const float* bf  = (const float*)d_in[3];
    const float* Wi  = (const float*)d_in[4];
    const float* bi  = (const float*)d_in[5];
    const float* Wu  = (const float*)d_in[6];
    const float* bu  = (const float*)d_in[7];
    const float* Wo  = (const float*)d_in[8];
    const float* bo  = (const float*)d_in[9];
    const float* pf  = (const float*)d_in[10];
    const float* pi  = (const float*)d_in[11];
    const float* pu  = (const float*)d_in[12];
    const float* po  = (const float*)d_in[13];
    const float* qkp = (const float*)d_in[14];

    float* out     = (float*)d_out;
    float* out_h   = out;
    float* out_rbf = out + OUT_H_SZ;
    float* out_qk  = out + OUT_H_SZ + OUT_RBF_SZ;

    float* pre = (float*)d_ws;   // 512 KB scratch (NROW*16 floats, in revolutions)

    pre_kernel<<<NROW / 16, 256, 0, stream>>>(x, Wf, bf, Wi, bi, Wu, bu, Wo, bo,
                                              pf, pi, pu, po, pre);
    fused_kernel<<<1 + 256, 512, 0, stream>>>(
        x, sv, Wf, bf, Wi, bi, Wu, bu, Wo, bo, pf, pi, pu, po, qkp, pre,
        out_h, out_rbf, out_qk);
}